// Round 5
// baseline (5273.554 us; speedup 1.0000x reference)
//
#include <hip/hip_runtime.h>
#include <hip/hip_bf16.h>
#include <cstdint>
#include <cstddef>

#define H   1024
#define D   80
#define DP  96          // D padded to multiple of 32 (zero-padded)
#define T   512
#define B   64
#define NGH 16          // gate rows per block PER DECODER (4 gates x 4 hidden units)
#define KP  1032        // LDS row stride for Whh slice (+8 bf16 pad)
#define KPI 104         // LDS row stride for Wih slice

typedef __attribute__((ext_vector_type(8))) short bf16x8;   // 8 bf16 (MFMA A/B frag)
typedef __attribute__((ext_vector_type(4))) float f32x4;    // MFMA C/D frag

// ws layout
#define HBUF_ELEMS ((size_t)2 * (T + 1) * B * H)            // bf16 h history, slot 0 = h_{-1}=0
#define HBUF_BYTES (HBUF_ELEMS * 2)
#define XS_ELEMS   ((size_t)T * B * DP)                     // bf16 teacher-forced inputs (padded)
#define XS_BYTES   (XS_ELEMS * 2)
#define WOUT_ELEMS ((size_t)2 * D * H)                      // bf16 W_out both decoders
#define WOUT_BYTES (WOUT_ELEMS * 2)
#define NFLAG      512                                       // flags[dec*256 + bid], 4B each

__device__ __forceinline__ unsigned short f2bf(float x) {
    unsigned int u = __float_as_uint(x);
    unsigned int r = (u + 0x7FFFu + ((u >> 16) & 1u)) >> 16;   // RNE
    return (unsigned short)r;
}

// overflow-safe fast tanh: 2*sigmoid(2x)-1 (x->+inf: exp->0 -> 1; x->-inf: exp->inf -> -1)
__device__ __forceinline__ float fast_tanh(float x) {
    return 2.f / (1.f + __expf(-2.f * x)) - 1.f;
}

// agent-scope (coherence-point) 8-byte store: sc1 path, bypasses L1/L2 write-back.
__device__ __forceinline__ void coh_store8(unsigned long long* p, unsigned long long v) {
    __hip_atomic_store(p, v, __ATOMIC_RELAXED, __HIP_MEMORY_SCOPE_AGENT);
}

// ---- prep: x0 = input[T-1] @ W_in^T + b_in ----
__global__ void prep_x0(const float* __restrict__ inp, const float* __restrict__ Win,
                        const float* __restrict__ bin, unsigned short* __restrict__ xs)
{
    int o = blockIdx.x;                // 0 .. B*D-1
    int b = o / D, d = o % D;
    int lane = threadIdx.x;
    const float* irow = inp + ((size_t)(T - 1) * B + b) * H;
    const float* wrow = Win + (size_t)d * H;
    float s = 0.f;
    for (int k = lane; k < H; k += 64) s += irow[k] * wrow[k];
    for (int off = 32; off > 0; off >>= 1) s += __shfl_down(s, off, 64);
    if (lane == 0) xs[b * DP + d] = f2bf(s + bin[d]);
}

// ---- prep: xs[t] = target[t-1] (t>=1), zero pads ----
__global__ void prep_xs(const float* __restrict__ tgt, unsigned short* __restrict__ xs)
{
    int idx = blockIdx.x * 256 + threadIdx.x;
    if (idx >= T * B * DP) return;
    int t = idx / (B * DP);
    int r = idx % (B * DP);
    int b = r / DP, d = r % DP;
    if (d >= D) { xs[idx] = 0; return; }
    if (t == 0) return;
    xs[idx] = f2bf(tgt[((size_t)(t - 1) * B + b) * D + d]);
}

// ---- prep: W_out->bf16, zero h slot 0, zero flags ----
__global__ void prep_misc(const float* __restrict__ fWout, const float* __restrict__ bWout,
                          unsigned short* __restrict__ woutbf, unsigned short* __restrict__ hbuf,
                          unsigned int* __restrict__ flags)
{
    int idx = blockIdx.x * 256 + threadIdx.x;
    const int NW = 2 * D * H;
    const int NZ = 2 * B * H;
    if (idx < NW) {
        int dec = idx / (D * H); int rr = idx % (D * H);
        woutbf[idx] = f2bf((dec ? bWout : fWout)[rr]);
    } else if (idx < NW + NZ) {
        int z = idx - NW;
        int dec = z / (B * H); int rr = z % (B * H);
        hbuf[(size_t)dec * (T + 1) * B * H + rr] = 0;
    } else if (idx < NW + NZ + NFLAG) {
        flags[idx - NW - NZ] = 0;
    }
}

// ---- main persistent kernel: 256 blocks x 256 threads (1 block/CU) ----
// Decoder-interleaved schedule: every block owns 4 hidden units of BOTH
// decoders; phases alternate F(t), B(t), F(t+1)... so each decoder's
// publish->flag->read round trip hides under the OTHER decoder's compute.
__global__ void __launch_bounds__(256, 1)
lstm_main(unsigned short* __restrict__ hbuf,
          const unsigned short* __restrict__ xs,
          const unsigned short* __restrict__ woutbf,
          unsigned int* __restrict__ flags,
          const float* __restrict__ fWih, const float* __restrict__ fWhh, const float* __restrict__ fbias,
          const float* __restrict__ bWih, const float* __restrict__ bWhh, const float* __restrict__ bbias,
          const float* __restrict__ fbout, const float* __restrict__ bbout,
          float* __restrict__ out)
{
    const int bid  = blockIdx.x;        // 0..255
    const int u0   = bid << 2;          // first of 4 owned hidden units (per decoder)
    const int tid  = threadIdx.x;
    const int wave = tid >> 6;
    const int lane = tid & 63;
    const int l15  = lane & 15;
    const int quad = lane >> 4;
    const int koff = quad * 8;

    __shared__ unsigned short sWhh[2][NGH][KP];    // 66 KB  (both decoders)
    __shared__ unsigned short sWih[2][NGH][KPI];   // 6.6 KB
    __shared__ float sBias[2][NGH];
    __shared__ float sG[B][17];                    // 16 gate-rows per phase
    __shared__ float sC[2][B][4];
    __shared__ unsigned long long sHq[B];          // packed 4-unit h slice (8B per batch)

    // ---- stage weights for BOTH decoders (row n: gate g=n>>2, unit j=n&3) ----
    for (int e = tid; e < 2 * NGH * H; e += 256) {
        int dc = e >> 14;                 // 16*1024 = 16384 per decoder
        int rem = e & 16383;
        int n = rem >> 10, k = rem & (H - 1);
        int row = (n >> 2) * H + u0 + (n & 3);
        const float* W = dc ? bWhh : fWhh;
        sWhh[dc][n][k] = f2bf(W[(size_t)row * H + k]);
    }
    for (int e = tid; e < 2 * NGH * KPI; e += 256) {
        int dc = e / (NGH * KPI); int rem = e % (NGH * KPI);
        int n = rem / KPI, dd = rem % KPI;
        int row = (n >> 2) * H + u0 + (n & 3);
        const float* W = dc ? bWih : fWih;
        sWih[dc][n][dd] = (dd < D) ? f2bf(W[(size_t)row * D + dd]) : 0;
    }
    if (tid < 2 * NGH) {
        int dc = tid >> 4, n = tid & 15;
        int row = (n >> 2) * H + u0 + (n & 3);
        sBias[dc][n] = (dc ? bbias : fbias)[row];
    }
    for (int e = tid; e < 2 * B * 4; e += 256) {
        int dc = e >> 8; int rem = e & 255;
        sC[dc][rem >> 2][rem & 3] = 0.f;
    }
    __syncthreads();

    const int m = wave * 16 + l15;   // batch row this lane loads for A-frags

    for (int t = 0; t < T; ++t) {
        #pragma unroll
        for (int dc = 0; dc < 2; ++dc) {
            // 1. wave0 polls this decoder's 256 producer flags (4/lane, dense).
            // Flags were set one full phase ago (other decoder's compute) so this
            // is expected to pass on the first iteration. Ordering: producers
            // drain h stores to the coherence point before their flag store;
            // write-once hbuf slots mean no stale cached lines (proven pattern).
            if (t > 0) {
                if (wave == 0) {
                    const unsigned int* pf = flags + dc * 256;
                    const unsigned need = (unsigned)t;
                    for (;;) {
                        unsigned f0 = __hip_atomic_load(&pf[lane],       __ATOMIC_RELAXED, __HIP_MEMORY_SCOPE_AGENT);
                        unsigned f1 = __hip_atomic_load(&pf[64 + lane],  __ATOMIC_RELAXED, __HIP_MEMORY_SCOPE_AGENT);
                        unsigned f2 = __hip_atomic_load(&pf[128 + lane], __ATOMIC_RELAXED, __HIP_MEMORY_SCOPE_AGENT);
                        unsigned f3 = __hip_atomic_load(&pf[192 + lane], __ATOMIC_RELAXED, __HIP_MEMORY_SCOPE_AGENT);
                        if (__all((f0 >= need) && (f1 >= need) && (f2 >= need) && (f3 >= need))) break;
                        __builtin_amdgcn_s_sleep(1);
                    }
                }
                __syncthreads();
            }

            // 2. issue ALL 32 h-loads into registers up-front (parallel misses:
            // one round-trip latency total instead of a shallow pipeline), then
            // run the LDS-only Wih MFMAs while they fly.
            const unsigned short* hrow =
                hbuf + ((size_t)(dc * (T + 1) + t) * B + m) * H + koff;
            bf16x8 A[32];
            #pragma unroll
            for (int kb = 0; kb < 32; ++kb) A[kb] = *(const bf16x8*)(hrow + kb * 32);

            f32x4 accA = {0.f, 0.f, 0.f, 0.f};
            f32x4 accB = {0.f, 0.f, 0.f, 0.f};
            const unsigned short* xrow = xs + ((size_t)t * B + m) * DP;
            #pragma unroll
            for (int kb = 0; kb < DP / 32; ++kb) {
                bf16x8 a  = *(const bf16x8*)(xrow + kb * 32 + koff);
                bf16x8 b0 = *(const bf16x8*)(&sWih[dc][l15][kb * 32 + koff]);
                accA = __builtin_amdgcn_mfma_f32_16x16x32_bf16(a, b0, accA, 0, 0, 0);
            }
            // two independent dep chains (even/odd kb) consuming loads in issue order
            #pragma unroll
            for (int kb = 0; kb < 16; ++kb) {
                bf16x8 w0 = *(const bf16x8*)(&sWhh[dc][l15][(2 * kb) * 32 + koff]);
                bf16x8 w1 = *(const bf16x8*)(&sWhh[dc][l15][(2 * kb + 1) * 32 + koff]);
                accA = __builtin_amdgcn_mfma_f32_16x16x32_bf16(A[2 * kb],     w0, accA, 0, 0, 0);
                accB = __builtin_amdgcn_mfma_f32_16x16x32_bf16(A[2 * kb + 1], w1, accB, 0, 0, 0);
            }
            f32x4 acc = accA + accB;
            #pragma unroll
            for (int r = 0; r < 4; ++r) sG[wave * 16 + quad * 4 + r][l15] = acc[r];
            __syncthreads();

            // 3. gate math: exactly one (batch, unit) per thread
            {
                int b = tid >> 2, j = tid & 3;
                float gi = sG[b][j]      + sBias[dc][j];
                float gf = sG[b][4 + j]  + sBias[dc][4 + j];
                float gg = sG[b][8 + j]  + sBias[dc][8 + j];
                float go = sG[b][12 + j] + sBias[dc][12 + j];
                float i_ = 1.f / (1.f + __expf(-gi));
                float f_ = 1.f / (1.f + __expf(-gf));
                float g_ = fast_tanh(gg);
                float o_ = 1.f / (1.f + __expf(-go));
                float c  = f_ * sC[dc][b][j] + i_ * g_;
                sC[dc][b][j] = c;
                ((unsigned short*)&sHq[b])[j] = f2bf(o_ * fast_tanh(c));
            }
            __syncthreads();

            // 4. wave1 publishes the 4-unit slice (8B per batch row) on the sc1
            // path, drains ITS stores, then lane 64 stores the flag. Wave0 is
            // free to start the next phase's poll concurrently.
            if (wave == 1) {
                unsigned long long v = sHq[lane];
                unsigned long long* dst = (unsigned long long*)
                    (hbuf + ((size_t)(dc * (T + 1) + t + 1) * B + lane) * H + u0);
                coh_store8(dst, v);
                asm volatile("s_waitcnt vmcnt(0)" ::: "memory");
                if (lane == 0) {
                    __hip_atomic_store(&flags[dc * 256 + bid], (unsigned)(t + 1),
                                       __ATOMIC_RELAXED, __HIP_MEMORY_SCOPE_AGENT);
                }
            }
        }
    }

    // wait for BOTH decoders' 512 flags to reach T (output tiles span both)
    {
        if (wave == 0) {
            for (;;) {
                bool ok = true;
                #pragma unroll
                for (int i = 0; i < 8; ++i) {
                    unsigned f = __hip_atomic_load(&flags[i * 64 + lane], __ATOMIC_RELAXED,
                                                   __HIP_MEMORY_SCOPE_AGENT);
                    ok = ok && (f >= (unsigned)T);
                }
                if (__all(ok)) break;
                __builtin_amdgcn_s_sleep(1);
            }
            __builtin_amdgcn_fence(__ATOMIC_ACQUIRE, "agent");   // once per dispatch
        }
        __syncthreads();
    }

    // ---- output projection: Y[dec][t] = h @ W_out^T + b_out ----
    for (int qq = 0; qq < 4; ++qq) {
        int q    = bid * 4 + qq;          // 0 .. 1023
        int ydec = q >> 9;
        int yt   = q & 511;
        const float* bout = ydec ? bbout : fbout;
        const unsigned short* hr = hbuf + ((size_t)(ydec * (T + 1) + yt + 1) * B + m) * H;
        const unsigned short* wb = woutbf + (size_t)ydec * D * H;
        #pragma unroll
        for (int nt = 0; nt < 5; ++nt) {
            f32x4 acc = {0.f, 0.f, 0.f, 0.f};
            const unsigned short* wrow = wb + (size_t)(nt * 16 + l15) * H;
            #pragma unroll 8
            for (int kb = 0; kb < H / 32; ++kb) {
                bf16x8 a  = *(const bf16x8*)(hr + kb * 32 + koff);
                bf16x8 bf = *(const bf16x8*)(wrow + kb * 32 + koff);
                acc = __builtin_amdgcn_mfma_f32_16x16x32_bf16(a, bf, acc, 0, 0, 0);
            }
            float bo = bout[nt * 16 + l15];
            #pragma unroll
            for (int r = 0; r < 4; ++r) {
                int bb_ = wave * 16 + quad * 4 + r;
                out[((size_t)(ydec * T + yt) * B + bb_) * D + nt * 16 + l15] = acc[r] + bo;
            }
        }
    }
}

extern "C" void kernel_launch(void* const* d_in, const int* in_sizes, int n_in,
                              void* d_out, int out_size, void* d_ws, size_t ws_size,
                              hipStream_t stream)
{
    const float* input  = (const float*)d_in[0];
    const float* target = (const float*)d_in[1];
    const float* Win    = (const float*)d_in[2];
    const float* bin    = (const float*)d_in[3];
    const float* fWih   = (const float*)d_in[4];
    const float* fWhh   = (const float*)d_in[5];
    const float* fb     = (const float*)d_in[6];
    const float* fWout  = (const float*)d_in[7];
    const float* fbout  = (const float*)d_in[8];
    const float* bWih   = (const float*)d_in[9];
    const float* bWhh   = (const float*)d_in[10];
    const float* bb     = (const float*)d_in[11];
    const float* bWout  = (const float*)d_in[12];
    const float* bbout  = (const float*)d_in[13];
    float* out = (float*)d_out;

    unsigned short* hbuf  = (unsigned short*)d_ws;
    unsigned short* xsb   = (unsigned short*)((char*)d_ws + HBUF_BYTES);
    unsigned short* wout  = (unsigned short*)((char*)d_ws + HBUF_BYTES + XS_BYTES);
    unsigned int*   flags = (unsigned int*)((char*)d_ws + HBUF_BYTES + XS_BYTES + WOUT_BYTES);

    prep_x0<<<B * D, 64, 0, stream>>>(input, Win, bin, xsb);
    prep_xs<<<(T * B * DP + 255) / 256, 256, 0, stream>>>(target, xsb);
    {
        int n = 2 * D * H + 2 * B * H + NFLAG;
        prep_misc<<<(n + 255) / 256, 256, 0, stream>>>(fWout, bWout, wout, hbuf, flags);
    }

    void* args[] = { &hbuf, &xsb, &wout, &flags,
                     (void*)&fWih, (void*)&fWhh, (void*)&fb,
                     (void*)&bWih, (void*)&bWhh, (void*)&bb,
                     (void*)&fbout, (void*)&bbout, &out };
    hipLaunchCooperativeKernel((void*)lstm_main, dim3(256), dim3(256), args, 0, stream);
}

// Round 6
// 4729.913 us; speedup vs baseline: 1.1149x; 1.1149x over previous
//
#include <hip/hip_runtime.h>
#include <hip/hip_bf16.h>
#include <cstdint>
#include <cstddef>

#define H   1024
#define D   80
#define DP  96          // D padded to multiple of 32 (zero-padded)
#define T   512
#define B   64
#define NG  32          // gate rows per block (4 gates x 8 hidden units)
#define KP  1032        // LDS row stride for Whh slice (+8 bf16 pad)
#define KPI 104         // LDS row stride for Wih slice

typedef __attribute__((ext_vector_type(8))) short bf16x8;   // 8 bf16 (MFMA A/B frag)
typedef __attribute__((ext_vector_type(4))) float f32x4;    // MFMA C/D frag

// ws layout
#define HBUF_ELEMS ((size_t)2 * (T + 1) * B * H)            // bf16 h history, slot 0 = h_{-1}=0
#define HBUF_BYTES (HBUF_ELEMS * 2)
#define XS_ELEMS   ((size_t)T * B * DP)                     // bf16 teacher-forced inputs (padded)
#define XS_BYTES   (XS_ELEMS * 2)
#define WOUT_ELEMS ((size_t)2 * D * H)                      // bf16 W_out both decoders
#define WOUT_BYTES (WOUT_ELEMS * 2)
#define NFLAG      384   // [0..255] producer flags; [256] epoch dec0; [320] epoch dec1

__device__ __forceinline__ unsigned short f2bf(float x) {
    unsigned int u = __float_as_uint(x);
    unsigned int r = (u + 0x7FFFu + ((u >> 16) & 1u)) >> 16;   // RNE
    return (unsigned short)r;
}

// overflow-safe fast tanh: 2*sigmoid(2x)-1 (validated round 5, absmax unchanged)
__device__ __forceinline__ float fast_tanh(float x) {
    return 2.f / (1.f + __expf(-2.f * x)) - 1.f;
}

// agent-scope (coherence-point) 8-byte store: sc1 path, bypasses L1/L2 write-back.
__device__ __forceinline__ void coh_store8(unsigned long long* p, unsigned long long v) {
    __hip_atomic_store(p, v, __ATOMIC_RELAXED, __HIP_MEMORY_SCOPE_AGENT);
}

// ---- prep: x0 = input[T-1] @ W_in^T + b_in ----
__global__ void prep_x0(const float* __restrict__ inp, const float* __restrict__ Win,
                        const float* __restrict__ bin, unsigned short* __restrict__ xs)
{
    int o = blockIdx.x;                // 0 .. B*D-1
    int b = o / D, d = o % D;
    int lane = threadIdx.x;
    const float* irow = inp + ((size_t)(T - 1) * B + b) * H;
    const float* wrow = Win + (size_t)d * H;
    float s = 0.f;
    for (int k = lane; k < H; k += 64) s += irow[k] * wrow[k];
    for (int off = 32; off > 0; off >>= 1) s += __shfl_down(s, off, 64);
    if (lane == 0) xs[b * DP + d] = f2bf(s + bin[d]);
}

// ---- prep: xs[t] = target[t-1] (t>=1), zero pads ----
__global__ void prep_xs(const float* __restrict__ tgt, unsigned short* __restrict__ xs)
{
    int idx = blockIdx.x * 256 + threadIdx.x;
    if (idx >= T * B * DP) return;
    int t = idx / (B * DP);
    int r = idx % (B * DP);
    int b = r / DP, d = r % DP;
    if (d >= D) { xs[idx] = 0; return; }
    if (t == 0) return;
    xs[idx] = f2bf(tgt[((size_t)(t - 1) * B + b) * D + d]);
}

// ---- prep: W_out->bf16, zero h slot 0, zero flags/epochs ----
__global__ void prep_misc(const float* __restrict__ fWout, const float* __restrict__ bWout,
                          unsigned short* __restrict__ woutbf, unsigned short* __restrict__ hbuf,
                          unsigned int* __restrict__ flags)
{
    int idx = blockIdx.x * 256 + threadIdx.x;
    const int NW = 2 * D * H;
    const int NZ = 2 * B * H;
    if (idx < NW) {
        int dec = idx / (D * H); int rr = idx % (D * H);
        woutbf[idx] = f2bf((dec ? bWout : fWout)[rr]);
    } else if (idx < NW + NZ) {
        int z = idx - NW;
        int dec = z / (B * H); int rr = z % (B * H);
        hbuf[(size_t)dec * (T + 1) * B * H + rr] = 0;
    } else if (idx < NW + NZ + NFLAG) {
        flags[idx - NW - NZ] = 0;
    }
}

// ---- main persistent kernel: 256 blocks x 256 threads (1 block/CU) ----
// Sync topology: per decoder, ONE aggregator block (blk==0) polls the 128
// producer flags and publishes a single epoch word; the other 127 blocks
// poll that one word wave-uniformly (one MALL transaction per iteration).
// This removes the 256-block x 128-load poll storm that backpressured the
// flag lines at the coherence point (round-2/4 evidence).
__global__ void __launch_bounds__(256, 1)
lstm_main(unsigned short* __restrict__ hbuf,
          const unsigned short* __restrict__ xs,
          const unsigned short* __restrict__ woutbf,
          unsigned int* __restrict__ flags,
          const float* __restrict__ fWih, const float* __restrict__ fWhh, const float* __restrict__ fbias,
          const float* __restrict__ bWih, const float* __restrict__ bWhh, const float* __restrict__ bbias,
          const float* __restrict__ fbout, const float* __restrict__ bbout,
          float* __restrict__ out)
{
    const int bid  = blockIdx.x;
    const int dec  = bid >> 7;          // 0 = fwd, 1 = bwd
    const int blk  = bid & 127;
    const int u0   = blk << 3;          // first of 8 owned hidden units
    const int tid  = threadIdx.x;
    const int wave = tid >> 6;
    const int lane = tid & 63;
    const int l15  = lane & 15;
    const int quad = lane >> 4;
    const int koff = quad * 8;

    __shared__ unsigned short sWhh[NG][KP];    // 66 KB
    __shared__ unsigned short sWih[NG][KPI];   // 6.5 KB
    __shared__ float sBias[NG];
    __shared__ float sG[B][33];
    __shared__ float sC[B][8];
    __shared__ bf16x8 sH[B];                   // packed h slice for vector publish

    const float* Wih  = dec ? bWih  : fWih;
    const float* Whh  = dec ? bWhh  : fWhh;
    const float* bias = dec ? bbias : fbias;

    for (int e = tid; e < NG * H; e += 256) {
        int n = e >> 10, k = e & (H - 1);
        int row = (n >> 3) * H + u0 + (n & 7);
        sWhh[n][k] = f2bf(Whh[(size_t)row * H + k]);
    }
    for (int e = tid; e < NG * KPI; e += 256) {
        int n = e / KPI, dd = e % KPI;
        int row = (n >> 3) * H + u0 + (n & 7);
        sWih[n][dd] = (dd < D) ? f2bf(Wih[(size_t)row * D + dd]) : 0;
    }
    if (tid < NG) {
        int row = (tid >> 3) * H + u0 + (tid & 7);
        sBias[tid] = bias[row];
    }
    for (int e = tid; e < B * 8; e += 256) sC[e >> 3][e & 7] = 0.f;
    __syncthreads();

    const int m = wave * 16 + l15;   // batch row this lane loads for A-frags
    unsigned int* myflag = flags + bid;
    const unsigned int* pf = flags + dec * 128;   // this decoder's 128 producer flags
    unsigned int* epoch = flags + 256 + dec * 64; // this decoder's epoch word

    for (int t = 0; t < T; ++t) {
        f32x4 acc0 = {0.f, 0.f, 0.f, 0.f};
        f32x4 acc1 = {0.f, 0.f, 0.f, 0.f};

        // x_t @ Wih^T first — independent of h_t, hides in the wait window
        const unsigned short* xrow = xs + ((size_t)t * B + m) * DP;
        #pragma unroll
        for (int kb = 0; kb < DP / 32; ++kb) {
            bf16x8 a  = *(const bf16x8*)(xrow + kb * 32 + koff);
            bf16x8 b0 = *(const bf16x8*)(&sWih[l15][kb * 32 + koff]);
            bf16x8 b1 = *(const bf16x8*)(&sWih[16 + l15][kb * 32 + koff]);
            acc0 = __builtin_amdgcn_mfma_f32_16x16x32_bf16(a, b0, acc0, 0, 0, 0);
            acc1 = __builtin_amdgcn_mfma_f32_16x16x32_bf16(a, b1, acc1, 0, 0, 0);
        }

        // Detection. Aggregator (blk 0): wave0 polls all 128 producer flags
        // (2/lane), then lane0 publishes epoch=t. Consumers: wave0 polls the
        // single epoch word (same address across lanes -> one transaction).
        // Ordering chain (transitive, write-once hbuf slots, proven pattern):
        // h drained -> flag -> aggregator -> epoch -> consumer h read.
        if (t > 0) {
            if (wave == 0) {
                const unsigned need = (unsigned)t;
                if (blk == 0) {
                    for (;;) {
                        unsigned f0 = __hip_atomic_load(&pf[lane],      __ATOMIC_RELAXED,
                                                        __HIP_MEMORY_SCOPE_AGENT);
                        unsigned f1 = __hip_atomic_load(&pf[64 + lane], __ATOMIC_RELAXED,
                                                        __HIP_MEMORY_SCOPE_AGENT);
                        if (__all((f0 >= need) && (f1 >= need))) break;
                        __builtin_amdgcn_s_sleep(1);
                    }
                    if (lane == 0)
                        __hip_atomic_store(epoch, need, __ATOMIC_RELAXED,
                                           __HIP_MEMORY_SCOPE_AGENT);
                } else {
                    while (__hip_atomic_load(epoch, __ATOMIC_RELAXED,
                                             __HIP_MEMORY_SCOPE_AGENT) < need)
                        __builtin_amdgcn_s_sleep(1);
                }
            }
            __syncthreads();
        }

        // G[64 x 32] += h_t @ Whh_slice^T (K = 1024), plain 16B vector loads
        {
            const unsigned short* hrow =
                hbuf + ((size_t)(dec * (T + 1) + t) * B + m) * H + koff;
            #pragma unroll 16
            for (int kb = 0; kb < H / 32; ++kb) {
                bf16x8 a  = *(const bf16x8*)(hrow + kb * 32);
                bf16x8 b0 = *(const bf16x8*)(&sWhh[l15][kb * 32 + koff]);
                bf16x8 b1 = *(const bf16x8*)(&sWhh[16 + l15][kb * 32 + koff]);
                acc0 = __builtin_amdgcn_mfma_f32_16x16x32_bf16(a, b0, acc0, 0, 0, 0);
                acc1 = __builtin_amdgcn_mfma_f32_16x16x32_bf16(a, b1, acc1, 0, 0, 0);
            }
        }
        #pragma unroll
        for (int r = 0; r < 4; ++r) {
            sG[wave * 16 + quad * 4 + r][l15]      = acc0[r];
            sG[wave * 16 + quad * 4 + r][16 + l15] = acc1[r];
        }
        __syncthreads();

        // elementwise gate math; pack h slice into LDS
        #pragma unroll
        for (int p = tid; p < B * 8; p += 256) {
            int b = p >> 3, j = p & 7;
            float gi = sG[b][j]      + sBias[j];
            float gf = sG[b][8 + j]  + sBias[8 + j];
            float gg = sG[b][16 + j] + sBias[16 + j];
            float go = sG[b][24 + j] + sBias[24 + j];
            float i_ = 1.f / (1.f + __expf(-gi));
            float f_ = 1.f / (1.f + __expf(-gf));
            float g_ = fast_tanh(gg);
            float o_ = 1.f / (1.f + __expf(-go));
            float c  = f_ * sC[b][j] + i_ * g_;
            sC[b][j] = c;
            ((unsigned short*)&sH[b])[j] = f2bf(o_ * fast_tanh(c));
        }
        __syncthreads();

        // wave 0 publishes the slice with sc1 agent stores, drains vmcnt
        // (orders h-stores before the flag at the coherence point), then
        // lane 0 relaxed-stores the flag. Flag stores now compete only with
        // the single aggregator's poll, not a 256-block storm.
        if (tid < 64) {
            const unsigned long long* src = (const unsigned long long*)&sH[tid];
            unsigned long long v0 = src[0], v1 = src[1];
            unsigned long long* dst = (unsigned long long*)
                (hbuf + ((size_t)(dec * (T + 1) + t + 1) * B + tid) * H + u0);
            coh_store8(dst, v0);
            coh_store8(dst + 1, v1);
            asm volatile("s_waitcnt vmcnt(0)" ::: "memory");
            if (lane == 0) {
                __hip_atomic_store(myflag, (unsigned)(t + 1), __ATOMIC_RELAXED,
                                   __HIP_MEMORY_SCOPE_AGENT);
            }
        }
    }

    // final: aggregators publish epoch=T, everyone waits on both epochs
    {
        if (blk == 0 && wave == 0) {
            const unsigned needT = (unsigned)T;
            for (;;) {
                unsigned f0 = __hip_atomic_load(&pf[lane],      __ATOMIC_RELAXED, __HIP_MEMORY_SCOPE_AGENT);
                unsigned f1 = __hip_atomic_load(&pf[64 + lane], __ATOMIC_RELAXED, __HIP_MEMORY_SCOPE_AGENT);
                if (__all((f0 >= needT) && (f1 >= needT))) break;
                __builtin_amdgcn_s_sleep(1);
            }
            if (lane == 0)
                __hip_atomic_store(epoch, needT, __ATOMIC_RELAXED, __HIP_MEMORY_SCOPE_AGENT);
        }
        if (wave == 0) {
            for (;;) {
                unsigned e0 = __hip_atomic_load(&flags[256], __ATOMIC_RELAXED, __HIP_MEMORY_SCOPE_AGENT);
                unsigned e1 = __hip_atomic_load(&flags[320], __ATOMIC_RELAXED, __HIP_MEMORY_SCOPE_AGENT);
                if (e0 >= (unsigned)T && e1 >= (unsigned)T) break;
                __builtin_amdgcn_s_sleep(1);
            }
            __builtin_amdgcn_fence(__ATOMIC_ACQUIRE, "agent");   // once per dispatch
        }
        __syncthreads();
    }

    // ---- output projection: Y[dec][t] = h @ W_out^T + b_out ----
    for (int qq = 0; qq < 4; ++qq) {
        int q    = bid * 4 + qq;          // 0 .. 1023
        int ydec = q >> 9;
        int yt   = q & 511;
        const float* bout = ydec ? bbout : fbout;
        const unsigned short* hr = hbuf + ((size_t)(ydec * (T + 1) + yt + 1) * B + m) * H;
        const unsigned short* wb = woutbf + (size_t)ydec * D * H;
        #pragma unroll
        for (int nt = 0; nt < 5; ++nt) {
            f32x4 acc = {0.f, 0.f, 0.f, 0.f};
            const unsigned short* wrow = wb + (size_t)(nt * 16 + l15) * H;
            #pragma unroll 8
            for (int kb = 0; kb < H / 32; ++kb) {
                bf16x8 a  = *(const bf16x8*)(hr + kb * 32 + koff);
                bf16x8 bf = *(const bf16x8*)(wrow + kb * 32 + koff);
                acc = __builtin_amdgcn_mfma_f32_16x16x32_bf16(a, bf, acc, 0, 0, 0);
            }
            float bo = bout[nt * 16 + l15];
            #pragma unroll
            for (int r = 0; r < 4; ++r) {
                int bb_ = wave * 16 + quad * 4 + r;
                out[((size_t)(ydec * T + yt) * B + bb_) * D + nt * 16 + l15] = acc[r] + bo;
            }
        }
    }
}

extern "C" void kernel_launch(void* const* d_in, const int* in_sizes, int n_in,
                              void* d_out, int out_size, void* d_ws, size_t ws_size,
                              hipStream_t stream)
{
    const float* input  = (const float*)d_in[0];
    const float* target = (const float*)d_in[1];
    const float* Win    = (const float*)d_in[2];
    const float* bin    = (const float*)d_in[3];
    const float* fWih   = (const float*)d_in[4];
    const float* fWhh   = (const float*)d_in[5];
    const float* fb     = (const float*)d_in[6];
    const float* fWout  = (const float*)d_in[7];
    const float* fbout  = (const float*)d_in[8];
    const float* bWih   = (const float*)d_in[9];
    const float* bWhh   = (const float*)d_in[10];
    const float* bb     = (const float*)d_in[11];
    const float* bWout  = (const float*)d_in[12];
    const float* bbout  = (const float*)d_in[13];
    float* out = (float*)d_out;

    unsigned short* hbuf  = (unsigned short*)d_ws;
    unsigned short* xsb   = (unsigned short*)((char*)d_ws + HBUF_BYTES);
    unsigned short* wout  = (unsigned short*)((char*)d_ws + HBUF_BYTES + XS_BYTES);
    unsigned int*   flags = (unsigned int*)((char*)d_ws + HBUF_BYTES + XS_BYTES + WOUT_BYTES);

    prep_x0<<<B * D, 64, 0, stream>>>(input, Win, bin, xsb);
    prep_xs<<<(T * B * DP + 255) / 256, 256, 0, stream>>>(target, xsb);
    {
        int n = 2 * D * H + 2 * B * H + NFLAG;
        prep_misc<<<(n + 255) / 256, 256, 0, stream>>>(fWout, bWout, wout, hbuf, flags);
    }

    void* args[] = { &hbuf, &xsb, &wout, &flags,
                     (void*)&fWih, (void*)&fWhh, (void*)&fb,
                     (void*)&bWih, (void*)&bWhh, (void*)&bb,
                     (void*)&fbout, (void*)&bbout, &out };
    hipLaunchCooperativeKernel((void*)lstm_main, dim3(256), dim3(256), args, 0, stream);
}

// Round 7
// 4669.278 us; speedup vs baseline: 1.1294x; 1.0130x over previous
//
#include <hip/hip_runtime.h>
#include <hip/hip_bf16.h>
#include <cstdint>
#include <cstddef>

#define H   1024
#define D   80
#define DP  96          // D padded to multiple of 32 (zero-padded)
#define T   512
#define B   64
#define NG  32          // gate rows per block (4 gates x 8 hidden units)
#define KP  1032        // LDS row stride for Whh slice (+8 bf16 pad)
#define KPI 104         // LDS row stride for Wih slice

typedef __attribute__((ext_vector_type(8))) short bf16x8;   // 8 bf16 (MFMA A/B frag)
typedef __attribute__((ext_vector_type(4))) float f32x4;    // MFMA C/D frag

// ws layout
#define HBUF_ELEMS ((size_t)2 * (T + 1) * B * H)            // bf16 h history, slot 0 = h_{-1}=0
#define HBUF_BYTES (HBUF_ELEMS * 2)
#define XS_ELEMS   ((size_t)T * B * DP)                     // bf16 teacher-forced inputs (padded)
#define XS_BYTES   (XS_ELEMS * 2)
#define WOUT_ELEMS ((size_t)2 * D * H)                      // bf16 W_out both decoders
#define WOUT_BYTES (WOUT_ELEMS * 2)
#define NFLAG      256                                       // flags[bid], 4B each (8B-aligned base)

__device__ __forceinline__ unsigned short f2bf(float x) {
    unsigned int u = __float_as_uint(x);
    unsigned int r = (u + 0x7FFFu + ((u >> 16) & 1u)) >> 16;   // RNE
    return (unsigned short)r;
}

// overflow-safe fast tanh: 2*sigmoid(2x)-1 (validated rounds 5/6, absmax unchanged)
__device__ __forceinline__ float fast_tanh(float x) {
    return 2.f / (1.f + __expf(-2.f * x)) - 1.f;
}

// agent-scope (coherence-point) 8-byte store: sc1 path, bypasses L1/L2 write-back.
__device__ __forceinline__ void coh_store8(unsigned long long* p, unsigned long long v) {
    __hip_atomic_store(p, v, __ATOMIC_RELAXED, __HIP_MEMORY_SCOPE_AGENT);
}

// ---- prep: x0 = input[T-1] @ W_in^T + b_in ----
__global__ void prep_x0(const float* __restrict__ inp, const float* __restrict__ Win,
                        const float* __restrict__ bin, unsigned short* __restrict__ xs)
{
    int o = blockIdx.x;                // 0 .. B*D-1
    int b = o / D, d = o % D;
    int lane = threadIdx.x;
    const float* irow = inp + ((size_t)(T - 1) * B + b) * H;
    const float* wrow = Win + (size_t)d * H;
    float s = 0.f;
    for (int k = lane; k < H; k += 64) s += irow[k] * wrow[k];
    for (int off = 32; off > 0; off >>= 1) s += __shfl_down(s, off, 64);
    if (lane == 0) xs[b * DP + d] = f2bf(s + bin[d]);
}

// ---- prep: xs[t] = target[t-1] (t>=1), zero pads ----
__global__ void prep_xs(const float* __restrict__ tgt, unsigned short* __restrict__ xs)
{
    int idx = blockIdx.x * 256 + threadIdx.x;
    if (idx >= T * B * DP) return;
    int t = idx / (B * DP);
    int r = idx % (B * DP);
    int b = r / DP, d = r % DP;
    if (d >= D) { xs[idx] = 0; return; }
    if (t == 0) return;
    xs[idx] = f2bf(tgt[((size_t)(t - 1) * B + b) * D + d]);
}

// ---- prep: W_out->bf16, zero h slot 0, zero flags ----
__global__ void prep_misc(const float* __restrict__ fWout, const float* __restrict__ bWout,
                          unsigned short* __restrict__ woutbf, unsigned short* __restrict__ hbuf,
                          unsigned int* __restrict__ flags)
{
    int idx = blockIdx.x * 256 + threadIdx.x;
    const int NW = 2 * D * H;
    const int NZ = 2 * B * H;
    if (idx < NW) {
        int dec = idx / (D * H); int rr = idx % (D * H);
        woutbf[idx] = f2bf((dec ? bWout : fWout)[rr]);
    } else if (idx < NW + NZ) {
        int z = idx - NW;
        int dec = z / (B * H); int rr = z % (B * H);
        hbuf[(size_t)dec * (T + 1) * B * H + rr] = 0;
    } else if (idx < NW + NZ + NFLAG) {
        flags[idx - NW - NZ] = 0;
    }
}

// ---- main persistent kernel: 256 blocks x 256 threads (1 block/CU) ----
__global__ void __launch_bounds__(256, 1)
lstm_main(unsigned short* __restrict__ hbuf,
          const unsigned short* __restrict__ xs,
          const unsigned short* __restrict__ woutbf,
          unsigned int* __restrict__ flags,
          const float* __restrict__ fWih, const float* __restrict__ fWhh, const float* __restrict__ fbias,
          const float* __restrict__ bWih, const float* __restrict__ bWhh, const float* __restrict__ bbias,
          const float* __restrict__ fbout, const float* __restrict__ bbout,
          float* __restrict__ out)
{
    const int bid  = blockIdx.x;
    const int dec  = bid >> 7;          // 0 = fwd, 1 = bwd
    const int blk  = bid & 127;
    const int u0   = blk << 3;          // first of 8 owned hidden units
    const int tid  = threadIdx.x;
    const int wave = tid >> 6;
    const int lane = tid & 63;
    const int l15  = lane & 15;
    const int quad = lane >> 4;
    const int koff = quad * 8;

    __shared__ unsigned short sWhh[NG][KP];    // 66 KB
    __shared__ unsigned short sWih[NG][KPI];   // 6.5 KB
    __shared__ float sBias[NG];
    __shared__ float sG[B][33];
    __shared__ float sC[B][8];
    __shared__ bf16x8 sH[B];                   // packed h slice for vector publish

    const float* Wih  = dec ? bWih  : fWih;
    const float* Whh  = dec ? bWhh  : fWhh;
    const float* bias = dec ? bbias : fbias;

    for (int e = tid; e < NG * H; e += 256) {
        int n = e >> 10, k = e & (H - 1);
        int row = (n >> 3) * H + u0 + (n & 7);
        sWhh[n][k] = f2bf(Whh[(size_t)row * H + k]);
    }
    for (int e = tid; e < NG * KPI; e += 256) {
        int n = e / KPI, dd = e % KPI;
        int row = (n >> 3) * H + u0 + (n & 7);
        sWih[n][dd] = (dd < D) ? f2bf(Wih[(size_t)row * D + dd]) : 0;
    }
    if (tid < NG) {
        int row = (tid >> 3) * H + u0 + (tid & 7);
        sBias[tid] = bias[row];
    }
    for (int e = tid; e < B * 8; e += 256) sC[e >> 3][e & 7] = 0.f;
    __syncthreads();

    const int m = wave * 16 + l15;   // batch row this lane loads for A-frags
    unsigned int* myflag = flags + bid;
    // packed poll: lane i reads ONE u64 covering producer flags (2i, 2i+1) of
    // this decoder -> one IC transaction per poll iteration (the R2 variant's
    // two separate atomic loads serialized as two IC trips per iteration).
    const unsigned long long* pw = (const unsigned long long*)(flags + dec * 128);

    for (int t = 0; t < T; ++t) {
        f32x4 acc0 = {0.f, 0.f, 0.f, 0.f};
        f32x4 acc1 = {0.f, 0.f, 0.f, 0.f};

        // x_t @ Wih^T first — independent of h_t, hides in the wait window
        const unsigned short* xrow = xs + ((size_t)t * B + m) * DP;
        #pragma unroll
        for (int kb = 0; kb < DP / 32; ++kb) {
            bf16x8 a  = *(const bf16x8*)(xrow + kb * 32 + koff);
            bf16x8 b0 = *(const bf16x8*)(&sWih[l15][kb * 32 + koff]);
            bf16x8 b1 = *(const bf16x8*)(&sWih[16 + l15][kb * 32 + koff]);
            acc0 = __builtin_amdgcn_mfma_f32_16x16x32_bf16(a, b0, acc0, 0, 0, 0);
            acc1 = __builtin_amdgcn_mfma_f32_16x16x32_bf16(a, b1, acc1, 0, 0, 0);
        }

        // wave 0 polls 128 producer flags as 64 u64 words (1 load/lane/iter),
        // pure spin (no s_sleep: immediate detection, keeps clocks up).
        // Ordering: producers drain h stores to the coherence point before the
        // flag store; write-once hbuf slots -> no stale cached lines (proven).
        if (t > 0) {
            if (wave == 0) {
                const unsigned need = (unsigned)t;
                for (;;) {
                    unsigned long long w = __hip_atomic_load(&pw[lane], __ATOMIC_RELAXED,
                                                             __HIP_MEMORY_SCOPE_AGENT);
                    unsigned lo = (unsigned)w, hi = (unsigned)(w >> 32);
                    if (__all((lo >= need) && (hi >= need))) break;
                }
            }
            __syncthreads();
        }

        // G[64 x 32] += h_t @ Whh_slice^T (K = 1024), plain 16B vector loads
        {
            const unsigned short* hrow =
                hbuf + ((size_t)(dec * (T + 1) + t) * B + m) * H + koff;
            #pragma unroll 16
            for (int kb = 0; kb < H / 32; ++kb) {
                bf16x8 a  = *(const bf16x8*)(hrow + kb * 32);
                bf16x8 b0 = *(const bf16x8*)(&sWhh[l15][kb * 32 + koff]);
                bf16x8 b1 = *(const bf16x8*)(&sWhh[16 + l15][kb * 32 + koff]);
                acc0 = __builtin_amdgcn_mfma_f32_16x16x32_bf16(a, b0, acc0, 0, 0, 0);
                acc1 = __builtin_amdgcn_mfma_f32_16x16x32_bf16(a, b1, acc1, 0, 0, 0);
            }
        }
        #pragma unroll
        for (int r = 0; r < 4; ++r) {
            sG[wave * 16 + quad * 4 + r][l15]      = acc0[r];
            sG[wave * 16 + quad * 4 + r][16 + l15] = acc1[r];
        }
        __syncthreads();

        // elementwise gate math; pack h slice into LDS
        #pragma unroll
        for (int p = tid; p < B * 8; p += 256) {
            int b = p >> 3, j = p & 7;
            float gi = sG[b][j]      + sBias[j];
            float gf = sG[b][8 + j]  + sBias[8 + j];
            float gg = sG[b][16 + j] + sBias[16 + j];
            float go = sG[b][24 + j] + sBias[24 + j];
            float i_ = 1.f / (1.f + __expf(-gi));
            float f_ = 1.f / (1.f + __expf(-gf));
            float g_ = fast_tanh(gg);
            float o_ = 1.f / (1.f + __expf(-go));
            float c  = f_ * sC[b][j] + i_ * g_;
            sC[b][j] = c;
            ((unsigned short*)&sH[b])[j] = f2bf(o_ * fast_tanh(c));
        }
        __syncthreads();

        // wave 0 publishes the slice with sc1 agent stores, drains vmcnt
        // (orders h-stores before the flag at the coherence point), then
        // lane 0 relaxed-stores the flag.
        if (tid < 64) {
            const unsigned long long* src = (const unsigned long long*)&sH[tid];
            unsigned long long v0 = src[0], v1 = src[1];
            unsigned long long* dst = (unsigned long long*)
                (hbuf + ((size_t)(dec * (T + 1) + t + 1) * B + tid) * H + u0);
            coh_store8(dst, v0);
            coh_store8(dst + 1, v1);
            asm volatile("s_waitcnt vmcnt(0)" ::: "memory");
            if (lane == 0) {
                __hip_atomic_store(myflag, (unsigned)(t + 1), __ATOMIC_RELAXED,
                                   __HIP_MEMORY_SCOPE_AGENT);
            }
        }
    }

    // wait for BOTH decoders to finish everything (output tiles span both)
    {
        if (wave == 0) {
            const unsigned needT = (unsigned)T;
            const unsigned long long* aw = (const unsigned long long*)flags;
            for (;;) {
                unsigned long long w0 = __hip_atomic_load(&aw[lane],      __ATOMIC_RELAXED, __HIP_MEMORY_SCOPE_AGENT);
                unsigned long long w1 = __hip_atomic_load(&aw[64 + lane], __ATOMIC_RELAXED, __HIP_MEMORY_SCOPE_AGENT);
                bool ok = ((unsigned)w0 >= needT) && ((unsigned)(w0 >> 32) >= needT) &&
                          ((unsigned)w1 >= needT) && ((unsigned)(w1 >> 32) >= needT);
                if (__all(ok)) break;
            }
            __builtin_amdgcn_fence(__ATOMIC_ACQUIRE, "agent");   // once per dispatch
        }
        __syncthreads();
    }

    // ---- output projection: Y[dec][t] = h @ W_out^T + b_out ----
    for (int qq = 0; qq < 4; ++qq) {
        int q    = bid * 4 + qq;          // 0 .. 1023
        int ydec = q >> 9;
        int yt   = q & 511;
        const float* bout = ydec ? bbout : fbout;
        const unsigned short* hr = hbuf + ((size_t)(ydec * (T + 1) + yt + 1) * B + m) * H;
        const unsigned short* wb = woutbf + (size_t)ydec * D * H;
        #pragma unroll
        for (int nt = 0; nt < 5; ++nt) {
            f32x4 acc = {0.f, 0.f, 0.f, 0.f};
            const unsigned short* wrow = wb + (size_t)(nt * 16 + l15) * H;
            #pragma unroll 8
            for (int kb = 0; kb < H / 32; ++kb) {
                bf16x8 a  = *(const bf16x8*)(hr + kb * 32 + koff);
                bf16x8 bf = *(const bf16x8*)(wrow + kb * 32 + koff);
                acc = __builtin_amdgcn_mfma_f32_16x16x32_bf16(a, bf, acc, 0, 0, 0);
            }
            float bo = bout[nt * 16 + l15];
            #pragma unroll
            for (int r = 0; r < 4; ++r) {
                int bb_ = wave * 16 + quad * 4 + r;
                out[((size_t)(ydec * T + yt) * B + bb_) * D + nt * 16 + l15] = acc[r] + bo;
            }
        }
    }
}

extern "C" void kernel_launch(void* const* d_in, const int* in_sizes, int n_in,
                              void* d_out, int out_size, void* d_ws, size_t ws_size,
                              hipStream_t stream)
{
    const float* input  = (const float*)d_in[0];
    const float* target = (const float*)d_in[1];
    const float* Win    = (const float*)d_in[2];
    const float* bin    = (const float*)d_in[3];
    const float* fWih   = (const float*)d_in[4];
    const float* fWhh   = (const float*)d_in[5];
    const float* fb     = (const float*)d_in[6];
    const float* fWout  = (const float*)d_in[7];
    const float* fbout  = (const float*)d_in[8];
    const float* bWih   = (const float*)d_in[9];
    const float* bWhh   = (const float*)d_in[10];
    const float* bb     = (const float*)d_in[11];
    const float* bWout  = (const float*)d_in[12];
    const float* bbout  = (const float*)d_in[13];
    float* out = (float*)d_out;

    unsigned short* hbuf  = (unsigned short*)d_ws;
    unsigned short* xsb   = (unsigned short*)((char*)d_ws + HBUF_BYTES);
    unsigned short* wout  = (unsigned short*)((char*)d_ws + HBUF_BYTES + XS_BYTES);
    unsigned int*   flags = (unsigned int*)((char*)d_ws + HBUF_BYTES + XS_BYTES + WOUT_BYTES);

    prep_x0<<<B * D, 64, 0, stream>>>(input, Win, bin, xsb);
    prep_xs<<<(T * B * DP + 255) / 256, 256, 0, stream>>>(target, xsb);
    {
        int n = 2 * D * H + 2 * B * H + NFLAG;
        prep_misc<<<(n + 255) / 256, 256, 0, stream>>>(fWout, bWout, wout, hbuf, flags);
    }

    void* args[] = { &hbuf, &xsb, &wout, &flags,
                     (void*)&fWih, (void*)&fWhh, (void*)&fb,
                     (void*)&bWih, (void*)&bWhh, (void*)&bb,
                     (void*)&fbout, (void*)&bbout, &out };
    hipLaunchCooperativeKernel((void*)lstm_main, dim3(256), dim3(256), args, 0, stream);
}

// Round 8
// 3745.237 us; speedup vs baseline: 1.4081x; 1.2467x over previous
//
#include <hip/hip_runtime.h>
#include <hip/hip_bf16.h>
#include <cstdint>
#include <cstddef>

#define H   1024
#define D   80
#define DP  96          // D padded to multiple of 32 (zero-padded)
#define T   512
#define B   64
#define NG  32          // gate rows per block (4 gates x 8 hidden units)
#define KP  1032        // LDS row stride for Whh slice (+8 bf16 pad)
#define KPI 104         // LDS row stride for Wih slice

typedef __attribute__((ext_vector_type(8))) short bf16x8;   // 8 bf16 (MFMA A/B frag)
typedef __attribute__((ext_vector_type(4))) float f32x4;    // MFMA C/D frag

// ws layout
#define HBUF_ELEMS ((size_t)2 * (T + 1) * B * H)            // bf16 h history, slot 0 = h_{-1}=0
#define HBUF_BYTES (HBUF_ELEMS * 2)
#define XS_ELEMS   ((size_t)T * B * DP)                     // bf16 teacher-forced inputs (padded)
#define XS_BYTES   (XS_ELEMS * 2)
#define WOUT_ELEMS ((size_t)2 * D * H)                      // bf16 W_out both decoders
#define WOUT_BYTES (WOUT_ELEMS * 2)
#define NFLAG      256                                       // flags[bid], 4B each (8B-aligned base)

__device__ __forceinline__ unsigned short f2bf(float x) {
    unsigned int u = __float_as_uint(x);
    unsigned int r = (u + 0x7FFFu + ((u >> 16) & 1u)) >> 16;   // RNE
    return (unsigned short)r;
}

// overflow-safe fast tanh: 2*sigmoid(2x)-1 (validated rounds 5-7, absmax unchanged)
__device__ __forceinline__ float fast_tanh(float x) {
    return 2.f / (1.f + __expf(-2.f * x)) - 1.f;
}

// agent-scope (coherence-point) 8-byte store: sc1 path, bypasses L1/L2 write-back.
__device__ __forceinline__ void coh_store8(unsigned long long* p, unsigned long long v) {
    __hip_atomic_store(p, v, __ATOMIC_RELAXED, __HIP_MEMORY_SCOPE_AGENT);
}

// ---- prep: x0 = input[T-1] @ W_in^T + b_in ----
__global__ void prep_x0(const float* __restrict__ inp, const float* __restrict__ Win,
                        const float* __restrict__ bin, unsigned short* __restrict__ xs)
{
    int o = blockIdx.x;                // 0 .. B*D-1
    int b = o / D, d = o % D;
    int lane = threadIdx.x;
    const float* irow = inp + ((size_t)(T - 1) * B + b) * H;
    const float* wrow = Win + (size_t)d * H;
    float s = 0.f;
    for (int k = lane; k < H; k += 64) s += irow[k] * wrow[k];
    for (int off = 32; off > 0; off >>= 1) s += __shfl_down(s, off, 64);
    if (lane == 0) xs[b * DP + d] = f2bf(s + bin[d]);
}

// ---- prep: xs[t] = target[t-1] (t>=1), zero pads ----
__global__ void prep_xs(const float* __restrict__ tgt, unsigned short* __restrict__ xs)
{
    int idx = blockIdx.x * 256 + threadIdx.x;
    if (idx >= T * B * DP) return;
    int t = idx / (B * DP);
    int r = idx % (B * DP);
    int b = r / DP, d = r % DP;
    if (d >= D) { xs[idx] = 0; return; }
    if (t == 0) return;
    xs[idx] = f2bf(tgt[((size_t)(t - 1) * B + b) * D + d]);
}

// ---- prep: W_out->bf16, zero h slot 0, zero flags ----
__global__ void prep_misc(const float* __restrict__ fWout, const float* __restrict__ bWout,
                          unsigned short* __restrict__ woutbf, unsigned short* __restrict__ hbuf,
                          unsigned int* __restrict__ flags)
{
    int idx = blockIdx.x * 256 + threadIdx.x;
    const int NW = 2 * D * H;
    const int NZ = 2 * B * H;
    if (idx < NW) {
        int dec = idx / (D * H); int rr = idx % (D * H);
        woutbf[idx] = f2bf((dec ? bWout : fWout)[rr]);
    } else if (idx < NW + NZ) {
        int z = idx - NW;
        int dec = z / (B * H); int rr = z % (B * H);
        hbuf[(size_t)dec * (T + 1) * B * H + rr] = 0;
    } else if (idx < NW + NZ + NFLAG) {
        flags[idx - NW - NZ] = 0;
    }
}

// ---- main persistent kernel: 256 blocks x 256 threads (1 block/CU) ----
__global__ void __launch_bounds__(256, 1)
lstm_main(unsigned short* __restrict__ hbuf,
          const unsigned short* __restrict__ xs,
          const unsigned short* __restrict__ woutbf,
          unsigned int* __restrict__ flags,
          const float* __restrict__ fWih, const float* __restrict__ fWhh, const float* __restrict__ fbias,
          const float* __restrict__ bWih, const float* __restrict__ bWhh, const float* __restrict__ bbias,
          const float* __restrict__ fbout, const float* __restrict__ bbout,
          float* __restrict__ out)
{
    const int bid  = blockIdx.x;
    const int dec  = bid >> 7;          // 0 = fwd, 1 = bwd
    const int blk  = bid & 127;
    const int u0   = blk << 3;          // first of 8 owned hidden units
    const int tid  = threadIdx.x;
    const int wave = tid >> 6;
    const int lane = tid & 63;
    const int l15  = lane & 15;
    const int quad = lane >> 4;
    const int koff = quad * 8;

    __shared__ unsigned short sWhh[NG][KP];    // 66 KB
    __shared__ unsigned short sWih[NG][KPI];   // 6.5 KB
    __shared__ float sBias[NG];
    __shared__ float sG[B][33];
    __shared__ float sC[B][8];
    __shared__ bf16x8 sH[B];                   // packed h slice for vector publish

    const float* Wih  = dec ? bWih  : fWih;
    const float* Whh  = dec ? bWhh  : fWhh;
    const float* bias = dec ? bbias : fbias;

    for (int e = tid; e < NG * H; e += 256) {
        int n = e >> 10, k = e & (H - 1);
        int row = (n >> 3) * H + u0 + (n & 7);
        sWhh[n][k] = f2bf(Whh[(size_t)row * H + k]);
    }
    for (int e = tid; e < NG * KPI; e += 256) {
        int n = e / KPI, dd = e % KPI;
        int row = (n >> 3) * H + u0 + (n & 7);
        sWih[n][dd] = (dd < D) ? f2bf(Wih[(size_t)row * D + dd]) : 0;
    }
    if (tid < NG) {
        int row = (tid >> 3) * H + u0 + (tid & 7);
        sBias[tid] = bias[row];
    }
    for (int e = tid; e < B * 8; e += 256) sC[e >> 3][e & 7] = 0.f;
    __syncthreads();

    const int m = wave * 16 + l15;   // batch row this lane loads for A-frags
    unsigned int* myflag = flags + bid;
    // packed poll: lane i reads ONE u64 covering producer flags (2i, 2i+1)
    const unsigned long long* pw = (const unsigned long long*)(flags + dec * 128);

    for (int t = 0; t < T; ++t) {
        // 4 accumulator chains: even/odd k x (units 0-7 / 8-15 columns)
        f32x4 acc0e = {0.f,0.f,0.f,0.f}, acc0o = {0.f,0.f,0.f,0.f};
        f32x4 acc1e = {0.f,0.f,0.f,0.f}, acc1o = {0.f,0.f,0.f,0.f};

        // x_t @ Wih^T first — independent of h_t, hides in the wait window
        const unsigned short* xrow = xs + ((size_t)t * B + m) * DP;
        #pragma unroll
        for (int kb = 0; kb < DP / 32; ++kb) {
            bf16x8 a  = *(const bf16x8*)(xrow + kb * 32 + koff);
            bf16x8 b0 = *(const bf16x8*)(&sWih[l15][kb * 32 + koff]);
            bf16x8 b1 = *(const bf16x8*)(&sWih[16 + l15][kb * 32 + koff]);
            acc0e = __builtin_amdgcn_mfma_f32_16x16x32_bf16(a, b0, acc0e, 0, 0, 0);
            acc1e = __builtin_amdgcn_mfma_f32_16x16x32_bf16(a, b1, acc1e, 0, 0, 0);
        }

        // wave 0 polls 128 producer flags as 64 u64 words, pure spin.
        // Ordering: producers drain h stores to the coherence point before the
        // flag store; write-once hbuf slots -> no stale cached lines (proven).
        if (t > 0) {
            if (wave == 0) {
                const unsigned need = (unsigned)t;
                for (;;) {
                    unsigned long long w = __hip_atomic_load(&pw[lane], __ATOMIC_RELAXED,
                                                             __HIP_MEMORY_SCOPE_AGENT);
                    unsigned lo = (unsigned)w, hi = (unsigned)(w >> 32);
                    if (__all((lo >= need) && (hi >= need))) break;
                }
            }
            __syncthreads();
        }

        // G[64 x 32] += h_t @ Whh_slice^T (K = 1024).
        // CLUSTERED LOADS: issue all 32 h-fragment loads back-to-back so they
        // overlap as one round trip + L2-BW streaming, then pin the schedule
        // with sched_barrier(0) so the machine scheduler cannot sink the loads
        // back to their uses (R5's hoist failed exactly that way; rule #18).
        {
            const unsigned short* hrow =
                hbuf + ((size_t)(dec * (T + 1) + t) * B + m) * H + koff;
            bf16x8 A[32];
            #pragma unroll
            for (int kb = 0; kb < 32; ++kb)
                A[kb] = *(const bf16x8*)(hrow + kb * 32);
            __builtin_amdgcn_sched_barrier(0);
            #pragma unroll
            for (int kb = 0; kb < 32; kb += 2) {
                bf16x8 b0a = *(const bf16x8*)(&sWhh[l15][kb * 32 + koff]);
                bf16x8 b1a = *(const bf16x8*)(&sWhh[16 + l15][kb * 32 + koff]);
                bf16x8 b0b = *(const bf16x8*)(&sWhh[l15][(kb + 1) * 32 + koff]);
                bf16x8 b1b = *(const bf16x8*)(&sWhh[16 + l15][(kb + 1) * 32 + koff]);
                acc0e = __builtin_amdgcn_mfma_f32_16x16x32_bf16(A[kb],     b0a, acc0e, 0, 0, 0);
                acc1e = __builtin_amdgcn_mfma_f32_16x16x32_bf16(A[kb],     b1a, acc1e, 0, 0, 0);
                acc0o = __builtin_amdgcn_mfma_f32_16x16x32_bf16(A[kb + 1], b0b, acc0o, 0, 0, 0);
                acc1o = __builtin_amdgcn_mfma_f32_16x16x32_bf16(A[kb + 1], b1b, acc1o, 0, 0, 0);
            }
        }
        f32x4 acc0 = acc0e + acc0o;
        f32x4 acc1 = acc1e + acc1o;
        #pragma unroll
        for (int r = 0; r < 4; ++r) {
            sG[wave * 16 + quad * 4 + r][l15]      = acc0[r];
            sG[wave * 16 + quad * 4 + r][16 + l15] = acc1[r];
        }
        __syncthreads();

        // elementwise gate math; pack h slice into LDS
        #pragma unroll
        for (int p = tid; p < B * 8; p += 256) {
            int b = p >> 3, j = p & 7;
            float gi = sG[b][j]      + sBias[j];
            float gf = sG[b][8 + j]  + sBias[8 + j];
            float gg = sG[b][16 + j] + sBias[16 + j];
            float go = sG[b][24 + j] + sBias[24 + j];
            float i_ = 1.f / (1.f + __expf(-gi));
            float f_ = 1.f / (1.f + __expf(-gf));
            float g_ = fast_tanh(gg);
            float o_ = 1.f / (1.f + __expf(-go));
            float c  = f_ * sC[b][j] + i_ * g_;
            sC[b][j] = c;
            ((unsigned short*)&sH[b])[j] = f2bf(o_ * fast_tanh(c));
        }
        __syncthreads();

        // wave 0 publishes the slice with sc1 agent stores, drains vmcnt
        // (orders h-stores before the flag at the coherence point), then
        // lane 0 relaxed-stores the flag.
        if (tid < 64) {
            const unsigned long long* src = (const unsigned long long*)&sH[tid];
            unsigned long long v0 = src[0], v1 = src[1];
            unsigned long long* dst = (unsigned long long*)
                (hbuf + ((size_t)(dec * (T + 1) + t + 1) * B + tid) * H + u0);
            coh_store8(dst, v0);
            coh_store8(dst + 1, v1);
            asm volatile("s_waitcnt vmcnt(0)" ::: "memory");
            if (lane == 0) {
                __hip_atomic_store(myflag, (unsigned)(t + 1), __ATOMIC_RELAXED,
                                   __HIP_MEMORY_SCOPE_AGENT);
            }
        }
    }

    // wait for BOTH decoders to finish everything (output tiles span both)
    {
        if (wave == 0) {
            const unsigned needT = (unsigned)T;
            const unsigned long long* aw = (const unsigned long long*)flags;
            for (;;) {
                unsigned long long w0 = __hip_atomic_load(&aw[lane],      __ATOMIC_RELAXED, __HIP_MEMORY_SCOPE_AGENT);
                unsigned long long w1 = __hip_atomic_load(&aw[64 + lane], __ATOMIC_RELAXED, __HIP_MEMORY_SCOPE_AGENT);
                bool ok = ((unsigned)w0 >= needT) && ((unsigned)(w0 >> 32) >= needT) &&
                          ((unsigned)w1 >= needT) && ((unsigned)(w1 >> 32) >= needT);
                if (__all(ok)) break;
            }
            __builtin_amdgcn_fence(__ATOMIC_ACQUIRE, "agent");   // once per dispatch
        }
        __syncthreads();
    }

    // ---- output projection: Y[dec][t] = h @ W_out^T + b_out ----
    for (int qq = 0; qq < 4; ++qq) {
        int q    = bid * 4 + qq;          // 0 .. 1023
        int ydec = q >> 9;
        int yt   = q & 511;
        const float* bout = ydec ? bbout : fbout;
        const unsigned short* hr = hbuf + ((size_t)(ydec * (T + 1) + yt + 1) * B + m) * H;
        const unsigned short* wb = woutbf + (size_t)ydec * D * H;

        // hoist + cluster the h-row fragments: loaded once, reused for 5 nt tiles
        bf16x8 Ah[32];
        #pragma unroll
        for (int kb = 0; kb < 32; ++kb)
            Ah[kb] = *(const bf16x8*)(hr + kb * 32 + koff);
        __builtin_amdgcn_sched_barrier(0);

        #pragma unroll
        for (int nt = 0; nt < 5; ++nt) {
            f32x4 acc = {0.f, 0.f, 0.f, 0.f};
            const unsigned short* wrow = wb + (size_t)(nt * 16 + l15) * H;
            #pragma unroll 8
            for (int kb = 0; kb < H / 32; ++kb) {
                bf16x8 bf = *(const bf16x8*)(wrow + kb * 32 + koff);
                acc = __builtin_amdgcn_mfma_f32_16x16x32_bf16(Ah[kb], bf, acc, 0, 0, 0);
            }
            float bo = bout[nt * 16 + l15];
            #pragma unroll
            for (int r = 0; r < 4; ++r) {
                int bb_ = wave * 16 + quad * 4 + r;
                out[((size_t)(ydec * T + yt) * B + bb_) * D + nt * 16 + l15] = acc[r] + bo;
            }
        }
    }
}

extern "C" void kernel_launch(void* const* d_in, const int* in_sizes, int n_in,
                              void* d_out, int out_size, void* d_ws, size_t ws_size,
                              hipStream_t stream)
{
    const float* input  = (const float*)d_in[0];
    const float* target = (const float*)d_in[1];
    const float* Win    = (const float*)d_in[2];
    const float* bin    = (const float*)d_in[3];
    const float* fWih   = (const float*)d_in[4];
    const float* fWhh   = (const float*)d_in[5];
    const float* fb     = (const float*)d_in[6];
    const float* fWout  = (const float*)d_in[7];
    const float* fbout  = (const float*)d_in[8];
    const float* bWih   = (const float*)d_in[9];
    const float* bWhh   = (const float*)d_in[10];
    const float* bb     = (const float*)d_in[11];
    const float* bWout  = (const float*)d_in[12];
    const float* bbout  = (const float*)d_in[13];
    float* out = (float*)d_out;

    unsigned short* hbuf  = (unsigned short*)d_ws;
    unsigned short* xsb   = (unsigned short*)((char*)d_ws + HBUF_BYTES);
    unsigned short* wout  = (unsigned short*)((char*)d_ws + HBUF_BYTES + XS_BYTES);
    unsigned int*   flags = (unsigned int*)((char*)d_ws + HBUF_BYTES + XS_BYTES + WOUT_BYTES);

    prep_x0<<<B * D, 64, 0, stream>>>(input, Win, bin, xsb);
    prep_xs<<<(T * B * DP + 255) / 256, 256, 0, stream>>>(target, xsb);
    {
        int n = 2 * D * H + 2 * B * H + NFLAG;
        prep_misc<<<(n + 255) / 256, 256, 0, stream>>>(fWout, bWout, wout, hbuf, flags);
    }

    void* args[] = { &hbuf, &xsb, &wout, &flags,
                     (void*)&fWih, (void*)&fWhh, (void*)&fb,
                     (void*)&bWih, (void*)&bWhh, (void*)&bb,
                     (void*)&fbout, (void*)&bbout, &out };
    hipLaunchCooperativeKernel((void*)lstm_main, dim3(256), dim3(256), args, 0, stream);
}